// Round 8
// baseline (71.117 us; speedup 1.0000x reference)
//
#include <hip/hip_runtime.h>
#include <limits.h>

// Problem constants (fixed by reference setup_inputs)
#define W_IMG 320
#define H_IMG 240
#define N_VIEW 2            // B*V = 1*2
#define DX_ 192
#define DY_ 192
#define DZ_ 96
#define NVOX 80000
#define CFEAT 128
#define NSTEPS 156
#define NPIX (N_VIEW * H_IMG * W_IMG)   // 153600

#define NCELLS (DZ_ * DY_ * DX_)        // 3,538,944
#define WPR (DX_ / 32)                  // 6 words per x-row
#define NWORDS (NCELLS / 32)            // 110,592

// d_out float offsets (concatenated return order)
#define OFF_PROJ 0
#define OFF_IDX  (NPIX * CFEAT)            // 19,660,800
#define OFF_W    (OFF_IDX + NPIX * 8)      // 20,889,600
#define OFF_MAP  (OFF_W + NPIX * 8)        // 22,118,400

// ------- Kernel B: dilate directly from occ + zero out_map --------------
// dilated bit(x,y,z) = OR of (occ != -1) over (x..x+1, y..y+1, z..z+1),
// upper-clipped — identical to the reference's 8-corner validity OR.
__global__ __launch_bounds__(256) void dilate_direct_kernel(
    const int* __restrict__ occ, unsigned* __restrict__ dil,
    float* __restrict__ out_map)
{
    int w = blockIdx.x * 256 + threadIdx.x;     // one thread per output word
    // fold in: zero the 80000-float histogram (first 20000 threads, float4)
    if (w < NVOX / 4) ((float4*)out_map)[w] = make_float4(0.f, 0.f, 0.f, 0.f);
    if (w >= NWORDS) return;

    int wx = w % WPR;
    int y  = (w / WPR) % DY_;
    int z  = w / (WPR * DY_);
    unsigned acc = 0;
    #pragma unroll
    for (int dz = 0; dz < 2; ++dz) {
        int zz = z + dz;
        if (zz >= DZ_) continue;
        #pragma unroll
        for (int dy = 0; dy < 2; ++dy) {
            int yy = y + dy;
            if (yy >= DY_) continue;
            const int* row = occ + (zz * DY_ + yy) * DX_ + (wx << 5);
            const int4* r4 = (const int4*)row;   // 128B-aligned
            unsigned m = 0;
            #pragma unroll
            for (int k = 0; k < 8; ++k) {
                int4 q = r4[k];
                unsigned b = (unsigned)(q.x != -1)
                           | ((unsigned)(q.y != -1) << 1)
                           | ((unsigned)(q.z != -1) << 2)
                           | ((unsigned)(q.w != -1) << 3);
                m |= b << (k * 4);
            }
            unsigned nxt = (wx + 1 < WPR) ? (unsigned)(row[32] != -1) : 0u;
            acc |= m | (m >> 1) | (nxt << 31);
        }
    }
    dil[w] = acc;
}

// -------- Kernel M: mega — raycast (32 lanes/pixel) + fused gather ------
__device__ __forceinline__ bool slow_any(const int* __restrict__ occ,
                                         int ix, int iy, int iz)
{
    bool any = false;
    #pragma unroll
    for (int c = 0; c < 8; ++c) {
        int ddz = c >> 2, ddy = (c >> 1) & 1, ddx = c & 1;
        int cxl = ix + ddx, cyl = iy + ddy, czl = iz + ddz;
        bool inb = ((unsigned)cxl < DX_) & ((unsigned)cyl < DY_) & ((unsigned)czl < DZ_);
        int xc = min(max(cxl, 0), DX_ - 1);
        int yc = min(max(cyl, 0), DY_ - 1);
        int zc = min(max(czl, 0), DZ_ - 1);
        int idx = occ[(zc * DY_ + yc) * DX_ + xc];
        any = any | (inb & (idx != -1));
    }
    return any;
}

__global__ __launch_bounds__(256) void mega_kernel(
    const float* __restrict__ vm,     // (1,V,4,4)
    const float* __restrict__ intr,   // (1,V,4)
    const int*   __restrict__ occ,    // (DZ,DY,DX)
    const unsigned* __restrict__ dil, // dilated bitmask
    const float* __restrict__ feat,   // NVOX*CFEAT
    float* __restrict__ out_idx,      // NPIX*8 (float-encoded ints)
    float* __restrict__ out_w,        // NPIX*8
    float* __restrict__ proj)         // NPIX*CFEAT
{
    int t      = blockIdx.x * 256 + threadIdx.x;
    int pix    = t >> 5;               // 32 lanes per pixel
    int lane32 = t & 31;

    int v   = pix / (H_IMG * W_IMG);
    int rem = pix - v * (H_IMG * W_IMG);
    int h   = rem / W_IMG;
    int w   = rem - h * W_IMG;

    const float* M = vm + v * 16;
    const float* I = intr + v * 4;
    float fx = I[0], fy = I[1], cx = I[2], cy = I[3];
    float uu = (float)w + 0.5f;
    float vv = (float)h + 0.5f;
    // dirs_cam, each op individually rounded (match numpy fp32, no FMA)
    float dc0 = __fdiv_rn(__fsub_rn(uu, cx), fx);
    float dc1 = __fdiv_rn(__fsub_rn(vv, cy), fy);
    float dc2 = 1.0f;
    float dir0 = __fadd_rn(__fadd_rn(__fmul_rn(M[0], dc0), __fmul_rn(M[1], dc1)), __fmul_rn(M[2], dc2));
    float dir1 = __fadd_rn(__fadd_rn(__fmul_rn(M[4], dc0), __fmul_rn(M[5], dc1)), __fmul_rn(M[6], dc2));
    float dir2 = __fadd_rn(__fadd_rn(__fmul_rn(M[8], dc0), __fmul_rn(M[9], dc1)), __fmul_rn(M[10], dc2));
    float t0 = M[3], t1 = M[7], t2 = M[11];

    // -------- march: 32 steps per round, ONE load per lane per round ----
    int s_hit = INT_MAX;
    #pragma unroll 1
    for (int base = 0; base < NSTEPS; base += 32) {
        int s = base + lane32;
        float d  = __fadd_rn(2.0f, __fmul_rn(0.5f, (float)s)); // exact
        float px = __fsub_rn(__fadd_rn(t0, __fmul_rn(d, dir0)), 0.5f);
        float py = __fsub_rn(__fadd_rn(t1, __fmul_rn(d, dir1)), 0.5f);
        float pz = __fsub_rn(__fadd_rn(t2, __fmul_rn(d, dir2)), 0.5f);
        int ix = (int)floorf(px);
        int iy = (int)floorf(py);
        int iz = (int)floorf(pz);
        bool inb3 = ((unsigned)ix < DX_) & ((unsigned)iy < DY_) & ((unsigned)iz < DZ_);
        int addr = inb3 ? ((iz * DY_ + iy) * WPR + (ix >> 5)) : 0;
        unsigned wd = dil[addr];
        bool ok  = (s < NSTEPS);
        bool any = ok & inb3 & (bool)((wd >> (ix & 31)) & 1u);
        bool ns  = ok & !inb3 & (ix >= -1) & (ix < DX_) & (iy >= -1) & (iy < DY_)
                      & (iz >= -1) & (iz < DZ_);
        if (ns) any = any | slow_any(occ, ix, iy, iz);  // cold: shell cells only
        int sm = any ? s : INT_MAX;
        // min over the 32-lane group
        sm = min(sm, __shfl_xor(sm, 1));
        sm = min(sm, __shfl_xor(sm, 2));
        sm = min(sm, __shfl_xor(sm, 4));
        sm = min(sm, __shfl_xor(sm, 8));
        sm = min(sm, __shfl_xor(sm, 16));
        if (sm != INT_MAX) { s_hit = sm; break; }
    }

    int hit = 0;
    int bx = 0, by = 0, bz = 0;
    float fr0 = 0.f, fr1 = 0.f, fr2 = 0.f;
    if (s_hit != INT_MAX) {
        hit = 1;
        float d  = __fadd_rn(2.0f, __fmul_rn(0.5f, (float)s_hit));
        float px = __fsub_rn(__fadd_rn(t0, __fmul_rn(d, dir0)), 0.5f);
        float py = __fsub_rn(__fadd_rn(t1, __fmul_rn(d, dir1)), 0.5f);
        float pz = __fsub_rn(__fadd_rn(t2, __fmul_rn(d, dir2)), 0.5f);
        float fpx = floorf(px), fpy = floorf(py), fpz = floorf(pz);
        bx = (int)fpx; by = (int)fpy; bz = (int)fpz;
        fr0 = px - fpx; fr1 = py - fpy; fr2 = pz - fpz; // exact (Sterbenz)
    }

    // -------- finalize (all 32 lanes compute identically) ---------------
    float ws8[8];
    int   id8[8];
    float wsum = 0.0f;
    #pragma unroll
    for (int c = 0; c < 8; ++c) {
        float wk = 0.0f;
        int idv = -1;
        if (hit) {
            int ddz = c >> 2, ddy = (c >> 1) & 1, ddx = c & 1;
            int cxl = bx + ddx, cyl = by + ddy, czl = bz + ddz;
            bool inb = ((unsigned)cxl < DX_) & ((unsigned)cyl < DY_) & ((unsigned)czl < DZ_);
            int xc = min(max(cxl, 0), DX_ - 1);
            int yc = min(max(cyl, 0), DY_ - 1);
            int zc = min(max(czl, 0), DZ_ - 1);
            int idx = occ[(zc * DY_ + yc) * DX_ + xc];
            bool valid = inb & (idx != -1);
            float gw = ddz ? fr2 : (1.0f - fr2);
            gw = __fmul_rn(gw, ddy ? fr1 : (1.0f - fr1));
            gw = __fmul_rn(gw, ddx ? fr0 : (1.0f - fr0));
            if (valid) { wk = gw; idv = idx; }
        }
        ws8[c] = wk;
        id8[c] = idv;
        wsum = __fadd_rn(wsum, wk);   // sequential order k=0..7
    }
    float inv = __fdiv_rn(1.0f, __fadd_rn(wsum, 1e-8f));

    float wn[8];
    #pragma unroll
    for (int c = 0; c < 8; ++c) wn[c] = __fmul_rn(ws8[c], inv);

    // one float4 store by lanes 0-3 of each 32-group
    float4* w4 = (float4*)out_w;
    float4* i4 = (float4*)out_idx;
    if (lane32 == 0)      w4[pix * 2]     = make_float4(wn[0], wn[1], wn[2], wn[3]);
    else if (lane32 == 1) w4[pix * 2 + 1] = make_float4(wn[4], wn[5], wn[6], wn[7]);
    else if (lane32 == 2) i4[pix * 2]     = make_float4((float)id8[0], (float)id8[1], (float)id8[2], (float)id8[3]);
    else if (lane32 == 3) i4[pix * 2 + 1] = make_float4((float)id8[4], (float)id8[5], (float)id8[6], (float)id8[7]);

    // -------- fused gather: each lane owns 4 channels (float4) ----------
    const float4* f4 = (const float4*)feat;
    float4 acc = make_float4(0.f, 0.f, 0.f, 0.f);
    #pragma unroll
    for (int c = 0; c < 8; ++c) {
        if (wn[c] != 0.0f) {
            float4 f = f4[id8[c] * (CFEAT / 4) + lane32];
            acc.x += wn[c] * f.x;
            acc.y += wn[c] * f.y;
            acc.z += wn[c] * f.z;
            acc.w += wn[c] * f.w;
        }
    }
    ((float4*)proj)[pix * (CFEAT / 4) + lane32] = acc;
}

// ---------------- Kernel H: histogram, 64-pixel run-length aggregation --
__global__ __launch_bounds__(256) void histo_kernel(
    const float* __restrict__ out_idx, float* __restrict__ out_map)
{
    int t = blockIdx.x * 256 + threadIdx.x;   // one thread per pixel
    int lane = threadIdx.x & 63;
    const float4* i4 = (const float4*)out_idx;
    float4 a = i4[t * 2];
    float4 b = i4[t * 2 + 1];
    float ids[8] = {a.x, a.y, a.z, a.w, b.x, b.y, b.z, b.w};
    #pragma unroll
    for (int c = 0; c < 8; ++c) {
        int vid  = (int)ids[c];
        int prev = __shfl_up(vid, 1);
        bool leader = (lane == 0) || (vid != prev);
        unsigned long long lm = __ballot(leader);
        unsigned long long higher = (lane == 63) ? 0ULL : (lm >> (lane + 1));
        int cnt = higher ? __ffsll(higher) : (64 - lane);
        if (leader && vid >= 0) atomicAdd(&out_map[vid], (float)cnt);
    }
}

extern "C" void kernel_launch(void* const* d_in, const int* in_sizes, int n_in,
                              void* d_out, int out_size, void* d_ws, size_t ws_size,
                              hipStream_t stream) {
    const float* feat = (const float*)d_in[0];
    const float* vm   = (const float*)d_in[1];
    const float* intr = (const float*)d_in[2];
    const int*   occ  = (const int*)d_in[3];
    float* out = (float*)d_out;

    float* out_proj = out + OFF_PROJ;
    float* out_idx  = out + OFF_IDX;
    float* out_w    = out + OFF_W;
    float* out_map  = out + OFF_MAP;

    unsigned* dil = (unsigned*)d_ws;            // 442,368 B

    // dilate also zeroes out_map (stream order precedes histo's atomics)
    dilate_direct_kernel<<<(NWORDS + 255) / 256, 256, 0, stream>>>(
        occ, dil, out_map);

    mega_kernel<<<(NPIX * 32) / 256, 256, 0, stream>>>(
        vm, intr, occ, dil, feat, out_idx, out_w, out_proj);

    histo_kernel<<<(NPIX + 255) / 256, 256, 0, stream>>>(out_idx, out_map);
}

// Round 9
// 64.375 us; speedup vs baseline: 1.1047x; 1.1047x over previous
//
#include <hip/hip_runtime.h>
#include <limits.h>

// Problem constants (fixed by reference setup_inputs)
#define W_IMG 320
#define H_IMG 240
#define N_VIEW 2            // B*V = 1*2
#define DX_ 192
#define DY_ 192
#define DZ_ 96
#define NVOX 80000
#define CFEAT 128
#define NSTEPS 156
#define NPIX (N_VIEW * H_IMG * W_IMG)   // 153600

#define NCELLS (DZ_ * DY_ * DX_)        // 3,538,944
#define WPR (DX_ / 32)                  // 6 words per x-row
#define NWORDS (NCELLS / 32)            // 110,592

// d_out float offsets (concatenated return order)
#define OFF_PROJ 0
#define OFF_IDX  (NPIX * CFEAT)            // 19,660,800
#define OFF_W    (OFF_IDX + NPIX * 8)      // 20,889,600
#define OFF_MAP  (OFF_W + NPIX * 8)        // 22,118,400

// ------- Kernel B: dilate directly from occ + zero out_map --------------
// dilated bit(x,y,z) = OR of (occ != -1) over (x..x+1, y..y+1, z..z+1),
// upper-clipped — identical to the reference's 8-corner validity OR.
__global__ __launch_bounds__(256) void dilate_direct_kernel(
    const int* __restrict__ occ, unsigned* __restrict__ dil,
    float* __restrict__ out_map)
{
    int w = blockIdx.x * 256 + threadIdx.x;     // one thread per output word
    // fold in: zero the 80000-float histogram (first 20000 threads, float4)
    if (w < NVOX / 4) ((float4*)out_map)[w] = make_float4(0.f, 0.f, 0.f, 0.f);
    if (w >= NWORDS) return;

    int wx = w % WPR;
    int y  = (w / WPR) % DY_;
    int z  = w / (WPR * DY_);
    unsigned acc = 0;
    #pragma unroll
    for (int dz = 0; dz < 2; ++dz) {
        int zz = z + dz;
        if (zz >= DZ_) continue;
        #pragma unroll
        for (int dy = 0; dy < 2; ++dy) {
            int yy = y + dy;
            if (yy >= DY_) continue;
            const int* row = occ + (zz * DY_ + yy) * DX_ + (wx << 5);
            const int4* r4 = (const int4*)row;   // 128B-aligned
            unsigned m = 0;
            #pragma unroll
            for (int k = 0; k < 8; ++k) {
                int4 q = r4[k];
                unsigned b = (unsigned)(q.x != -1)
                           | ((unsigned)(q.y != -1) << 1)
                           | ((unsigned)(q.z != -1) << 2)
                           | ((unsigned)(q.w != -1) << 3);
                m |= b << (k * 4);
            }
            unsigned nxt = (wx + 1 < WPR) ? (unsigned)(row[32] != -1) : 0u;
            acc |= m | (m >> 1) | (nxt << 31);
        }
    }
    dil[w] = acc;
}

// -------- Kernel M: raycast (4 lanes/pixel) + fused gather --------------
__device__ __forceinline__ bool slow_any(const int* __restrict__ occ,
                                         int ix, int iy, int iz)
{
    bool any = false;
    #pragma unroll
    for (int c = 0; c < 8; ++c) {
        int ddz = c >> 2, ddy = (c >> 1) & 1, ddx = c & 1;
        int cxl = ix + ddx, cyl = iy + ddy, czl = iz + ddz;
        bool inb = ((unsigned)cxl < DX_) & ((unsigned)cyl < DY_) & ((unsigned)czl < DZ_);
        int xc = min(max(cxl, 0), DX_ - 1);
        int yc = min(max(cyl, 0), DY_ - 1);
        int zc = min(max(czl, 0), DZ_ - 1);
        int idx = occ[(zc * DY_ + yc) * DX_ + xc];
        any = any | (inb & (idx != -1));
    }
    return any;
}

__global__ __launch_bounds__(256) void mega_kernel(
    const float* __restrict__ vm,     // (1,V,4,4)
    const float* __restrict__ intr,   // (1,V,4)
    const int*   __restrict__ occ,    // (DZ,DY,DX)
    const unsigned* __restrict__ dil, // dilated bitmask
    const float* __restrict__ feat,   // NVOX*CFEAT
    float* __restrict__ out_idx,      // NPIX*8 (float-encoded ints)
    float* __restrict__ out_w,        // NPIX*8
    float* __restrict__ proj)         // NPIX*CFEAT
{
    int t    = blockIdx.x * 256 + threadIdx.x;
    int pix  = t >> 2;                 // 4 lanes per pixel
    int sub  = t & 3;

    int v   = pix / (H_IMG * W_IMG);
    int rem = pix - v * (H_IMG * W_IMG);
    int h   = rem / W_IMG;
    int w   = rem - h * W_IMG;

    const float* M = vm + v * 16;
    const float* I = intr + v * 4;
    float fx = I[0], fy = I[1], cx = I[2], cy = I[3];
    float uu = (float)w + 0.5f;
    float vv = (float)h + 0.5f;
    // dirs_cam, each op individually rounded (match numpy fp32, no FMA)
    float dc0 = __fdiv_rn(__fsub_rn(uu, cx), fx);
    float dc1 = __fdiv_rn(__fsub_rn(vv, cy), fy);
    float dc2 = 1.0f;
    float dir0 = __fadd_rn(__fadd_rn(__fmul_rn(M[0], dc0), __fmul_rn(M[1], dc1)), __fmul_rn(M[2], dc2));
    float dir1 = __fadd_rn(__fadd_rn(__fmul_rn(M[4], dc0), __fmul_rn(M[5], dc1)), __fmul_rn(M[6], dc2));
    float dir2 = __fadd_rn(__fadd_rn(__fmul_rn(M[8], dc0), __fmul_rn(M[9], dc1)), __fmul_rn(M[10], dc2));
    float t0 = M[3], t1 = M[7], t2 = M[11];

    // -------- march: 32-step window/round, 8 independent loads/lane ----
    int s_hit = INT_MAX;
    for (int base = 0; base < NSTEPS; base += 32) {
        int smin = INT_MAX;
        int need = 0;                          // deferred slow-path mask
        #pragma unroll
        for (int j = 0; j < 8; ++j) {
            int s = base + sub + 4 * j;
            float d  = __fadd_rn(2.0f, __fmul_rn(0.5f, (float)s)); // exact
            float px = __fsub_rn(__fadd_rn(t0, __fmul_rn(d, dir0)), 0.5f);
            float py = __fsub_rn(__fadd_rn(t1, __fmul_rn(d, dir1)), 0.5f);
            float pz = __fsub_rn(__fadd_rn(t2, __fmul_rn(d, dir2)), 0.5f);
            int ix = (int)floorf(px);
            int iy = (int)floorf(py);
            int iz = (int)floorf(pz);
            bool inb3 = ((unsigned)ix < DX_) & ((unsigned)iy < DY_) & ((unsigned)iz < DZ_);
            int addr = inb3 ? ((iz * DY_ + iy) * WPR + (ix >> 5)) : 0;
            unsigned wd = dil[addr];           // 8 independent loads in flight
            bool ok = (s < NSTEPS);
            bool any = ok & inb3 & (bool)((wd >> (ix & 31)) & 1u);
            bool ns  = ok & !inb3 & (ix >= -1) & (ix < DX_) & (iy >= -1) & (iy < DY_)
                          & (iz >= -1) & (iz < DZ_);
            need |= (ns ? 1 : 0) << j;
            if (any) smin = min(smin, s);
        }
        if (__builtin_expect(need, 0)) {       // cold: boundary cells only
            for (int j = 0; j < 8; ++j) {
                if ((need >> j) & 1) {
                    int s = base + sub + 4 * j;
                    float d  = __fadd_rn(2.0f, __fmul_rn(0.5f, (float)s));
                    float px = __fsub_rn(__fadd_rn(t0, __fmul_rn(d, dir0)), 0.5f);
                    float py = __fsub_rn(__fadd_rn(t1, __fmul_rn(d, dir1)), 0.5f);
                    float pz = __fsub_rn(__fadd_rn(t2, __fmul_rn(d, dir2)), 0.5f);
                    int ix = (int)floorf(px);
                    int iy = (int)floorf(py);
                    int iz = (int)floorf(pz);
                    if (slow_any(occ, ix, iy, iz)) smin = min(smin, s);
                }
            }
        }
        // min over the 4-lane group (xor 1,2 stay within the group)
        smin = min(smin, __shfl_xor(smin, 1));
        smin = min(smin, __shfl_xor(smin, 2));
        if (smin != INT_MAX) { s_hit = smin; break; }
    }

    int hit = 0;
    int bx = 0, by = 0, bz = 0;
    float fr0 = 0.f, fr1 = 0.f, fr2 = 0.f;
    if (s_hit != INT_MAX) {
        hit = 1;
        float d  = __fadd_rn(2.0f, __fmul_rn(0.5f, (float)s_hit));
        float px = __fsub_rn(__fadd_rn(t0, __fmul_rn(d, dir0)), 0.5f);
        float py = __fsub_rn(__fadd_rn(t1, __fmul_rn(d, dir1)), 0.5f);
        float pz = __fsub_rn(__fadd_rn(t2, __fmul_rn(d, dir2)), 0.5f);
        float fpx = floorf(px), fpy = floorf(py), fpz = floorf(pz);
        bx = (int)fpx; by = (int)fpy; bz = (int)fpz;
        fr0 = px - fpx; fr1 = py - fpy; fr2 = pz - fpz; // exact (Sterbenz)
    }

    // -------- finalize (all 4 lanes compute identically; loads broadcast)
    float ws8[8];
    int   id8[8];
    float wsum = 0.0f;
    #pragma unroll
    for (int c = 0; c < 8; ++c) {
        float wk = 0.0f;
        int idv = -1;
        if (hit) {
            int ddz = c >> 2, ddy = (c >> 1) & 1, ddx = c & 1;
            int cxl = bx + ddx, cyl = by + ddy, czl = bz + ddz;
            bool inb = ((unsigned)cxl < DX_) & ((unsigned)cyl < DY_) & ((unsigned)czl < DZ_);
            int xc = min(max(cxl, 0), DX_ - 1);
            int yc = min(max(cyl, 0), DY_ - 1);
            int zc = min(max(czl, 0), DZ_ - 1);
            int idx = occ[(zc * DY_ + yc) * DX_ + xc];
            bool valid = inb & (idx != -1);
            float gw = ddz ? fr2 : (1.0f - fr2);
            gw = __fmul_rn(gw, ddy ? fr1 : (1.0f - fr1));
            gw = __fmul_rn(gw, ddx ? fr0 : (1.0f - fr0));
            if (valid) { wk = gw; idv = idx; }
        }
        ws8[c] = wk;
        id8[c] = idv;
        wsum = __fadd_rn(wsum, wk);   // sequential order k=0..7
    }
    float inv = __fdiv_rn(1.0f, __fadd_rn(wsum, 1e-8f));

    float wn[8];
    #pragma unroll
    for (int c = 0; c < 8; ++c) wn[c] = __fmul_rn(ws8[c], inv);

    // one float4 store per lane (all 4 lanes active)
    float4* w4 = (float4*)out_w;
    float4* i4 = (float4*)out_idx;
    if (sub == 0)      w4[pix * 2]     = make_float4(wn[0], wn[1], wn[2], wn[3]);
    else if (sub == 1) w4[pix * 2 + 1] = make_float4(wn[4], wn[5], wn[6], wn[7]);
    else if (sub == 2) i4[pix * 2]     = make_float4((float)id8[0], (float)id8[1], (float)id8[2], (float)id8[3]);
    else               i4[pix * 2 + 1] = make_float4((float)id8[4], (float)id8[5], (float)id8[6], (float)id8[7]);

    // -------- fused gather: lane sub owns channels [sub*32, sub*32+32) --
    // 8 float4 per lane; group accesses are 512B-contiguous per corner.
    const float4* f4 = (const float4*)feat;
    float4 acc[8];
    #pragma unroll
    for (int k = 0; k < 8; ++k) acc[k] = make_float4(0.f, 0.f, 0.f, 0.f);
    #pragma unroll
    for (int c = 0; c < 8; ++c) {
        if (wn[c] != 0.0f) {
            const float4* fb = f4 + id8[c] * (CFEAT / 4) + sub * 8;
            #pragma unroll
            for (int k = 0; k < 8; ++k) {
                float4 f = fb[k];
                acc[k].x += wn[c] * f.x;
                acc[k].y += wn[c] * f.y;
                acc[k].z += wn[c] * f.z;
                acc[k].w += wn[c] * f.w;
            }
        }
    }
    float4* p4 = (float4*)proj + pix * (CFEAT / 4) + sub * 8;
    #pragma unroll
    for (int k = 0; k < 8; ++k) p4[k] = acc[k];
}

// ---------------- Kernel H: histogram, 64-pixel run-length aggregation --
__global__ __launch_bounds__(256) void histo_kernel(
    const float* __restrict__ out_idx, float* __restrict__ out_map)
{
    int t = blockIdx.x * 256 + threadIdx.x;   // one thread per pixel
    int lane = threadIdx.x & 63;
    const float4* i4 = (const float4*)out_idx;
    float4 a = i4[t * 2];
    float4 b = i4[t * 2 + 1];
    float ids[8] = {a.x, a.y, a.z, a.w, b.x, b.y, b.z, b.w};
    #pragma unroll
    for (int c = 0; c < 8; ++c) {
        int vid  = (int)ids[c];
        int prev = __shfl_up(vid, 1);
        bool leader = (lane == 0) || (vid != prev);
        unsigned long long lm = __ballot(leader);
        unsigned long long higher = (lane == 63) ? 0ULL : (lm >> (lane + 1));
        int cnt = higher ? __ffsll(higher) : (64 - lane);
        if (leader && vid >= 0) atomicAdd(&out_map[vid], (float)cnt);
    }
}

extern "C" void kernel_launch(void* const* d_in, const int* in_sizes, int n_in,
                              void* d_out, int out_size, void* d_ws, size_t ws_size,
                              hipStream_t stream) {
    const float* feat = (const float*)d_in[0];
    const float* vm   = (const float*)d_in[1];
    const float* intr = (const float*)d_in[2];
    const int*   occ  = (const int*)d_in[3];
    float* out = (float*)d_out;

    float* out_proj = out + OFF_PROJ;
    float* out_idx  = out + OFF_IDX;
    float* out_w    = out + OFF_W;
    float* out_map  = out + OFF_MAP;

    unsigned* dil = (unsigned*)d_ws;            // 442,368 B

    // dilate also zeroes out_map (stream order precedes histo's atomics)
    dilate_direct_kernel<<<(NWORDS + 255) / 256, 256, 0, stream>>>(
        occ, dil, out_map);

    mega_kernel<<<(NPIX * 4) / 256, 256, 0, stream>>>(
        vm, intr, occ, dil, feat, out_idx, out_w, out_proj);

    histo_kernel<<<(NPIX + 255) / 256, 256, 0, stream>>>(out_idx, out_map);
}